// Round 1
// baseline (267.018 us; speedup 1.0000x reference)
//
#include <hip/hip_runtime.h>
#include <math.h>

#define NPROJ 96
#define NANG  96
#define DET   192
#define HH    128
#define WW    128
#define NPIX  (HH*WW)          // 16384
#define SLICE (NANG*DET)       // 18432

// DSD/DU = DSD/DV = 1000/3.5
#define KPROJ 285.7142857142857f

__device__ __forceinline__ float frcp(float x) { return __builtin_amdgcn_rcpf(x); }

// ---------------------------------------------------------------------------
// K1: deriv = grad_lastdim(sino * weight), rows of 192 along detector dim
// ---------------------------------------------------------------------------
__global__ __launch_bounds__(192) void k_deriv(const float* __restrict__ sino,
                                               const float* __restrict__ wgt,
                                               float* __restrict__ deriv) {
    __shared__ float row[DET];
    const int r = blockIdx.x;          // p*96 + a, 0..9215
    const int d = threadIdx.x;         // 0..191
    const int base = r * DET + d;
    row[d] = sino[base] * wgt[base];
    __syncthreads();
    float g;
    if (d == 0)           g = row[1] - row[0];
    else if (d == DET-1)  g = row[DET-1] - row[DET-2];
    else                  g = 0.5f * (row[d+1] - row[d-1]);
    deriv[base] = g;
}

// ---------------------------------------------------------------------------
// K2: 2D backprojection over 96 angles + 3D cosine weighting.
// grid (96 p, 8 pixel-chunks), block 256. Full (96x192) deriv slice in LDS.
// pos = cos*x + sin*y + 95.5 is ALWAYS in [5.7, 185.3] -> no boundary masks.
// ---------------------------------------------------------------------------
__global__ __launch_bounds__(256) void k_bp2d(const float* __restrict__ deriv,
                                              float* __restrict__ wcb) {
    __shared__ float sd[SLICE];        // 73728 B
    __shared__ float sc[NANG], ss[NANG];
    const int p   = blockIdx.x;
    const int tid = threadIdx.x;

    // stage deriv slice (18432 floats = 4608 float4 = 18 per thread)
    {
        const float4* src = (const float4*)(deriv + p * SLICE);
        float4* dst = (float4*)sd;
        #pragma unroll
        for (int i = 0; i < (SLICE/4)/256; ++i)
            dst[tid + i*256] = src[tid + i*256];
    }
    if (tid < NANG) {
        float s_, c_;
        sincosf((float)tid * (float)(3.14159265358979323846 / 96.0), &s_, &c_);
        sc[tid] = c_; ss[tid] = s_;
    }
    __syncthreads();

    const int pixbase = blockIdx.y * 2048;
    float acc[8], fx[8], fy[8];
    #pragma unroll
    for (int i = 0; i < 8; ++i) {
        const int pix = pixbase + i*256 + tid;
        fx[i] = (float)(pix & 127) - 63.5f;
        fy[i] = (float)(pix >> 7)  - 63.5f;
        acc[i] = 0.0f;
    }

    for (int a = 0; a < NANG; ++a) {
        const float cb = sc[a], sb = ss[a];
        const float* rowp = sd + a * DET;
        #pragma unroll
        for (int i = 0; i < 8; ++i) {
            const float pos = cb * fx[i] + sb * fy[i] + 95.5f;
            const int   i0  = (int)pos;          // pos > 0 always
            const float f   = pos - (float)i0;
            const float g0  = rowp[i0];
            const float g1  = rowp[i0 + 1];
            acc[i] += fmaf(f, g1 - g0, g0);
        }
    }

    #pragma unroll
    for (int i = 0; i < 8; ++i) {
        const int pix = pixbase + i*256 + tid;
        const float w = 1000.0f * rsqrtf(1000000.0f + fx[i]*fx[i] + fy[i]*fy[i]);
        wcb[p * NPIX + pix] = acc[i] * w;
    }
}

// ---------------------------------------------------------------------------
// K3: 3D cone-beam backprojection + PReLU.
// grid (64 y-pairs, 8 z-chunks), block 256: thread = (x, y in pair), 16 z's.
// Per beta, stage only the v-row window needed by this z-chunk (<=25 rows,
// ~13 KB) into LDS. pu/pv always interior -> no masks.
// ---------------------------------------------------------------------------
__global__ __launch_bounds__(256) void k_bp3d(const float* __restrict__ wcb,
                                              const float* __restrict__ prelu,
                                              float* __restrict__ out) {
    __shared__ float sp[32 * 128];     // 16 KB row window
    __shared__ float sc[NPROJ], ss[NPROJ];
    const int tid = threadIdx.x;
    const int x   = tid & 127;
    const int y   = (blockIdx.x << 1) | (tid >> 7);
    const int z0  = blockIdx.y << 4;

    if (tid < NPROJ) {
        float s_, c_;
        sincosf((float)tid * (float)(2.0 * 3.14159265358979323846 / 96.0), &s_, &c_);
        sc[tid] = c_; ss[tid] = s_;
    }

    const float fx  = (float)x - 63.5f;
    const float fy  = (float)y - 63.5f;
    const float zlo = (float)z0 - 63.5f;
    const float zhi = zlo + 15.0f;

    // v-window for this z-chunk: pv = 63.5 + K*z', K in [0.4844, 0.6966]
    const float KMIN = 0.4843f, KMAX = 0.6967f;
    const float c0 = KMIN * zlo, c1 = KMAX * zlo, c2 = KMIN * zhi, c3 = KMAX * zhi;
    const float mn = fminf(fminf(c0, c1), fminf(c2, c3));
    const float mx = fmaxf(fmaxf(c0, c1), fmaxf(c2, c3));
    int vlo = (int)floorf(63.5f + mn) - 1;
    int vhi = (int)floorf(63.5f + mx) + 2;
    if (vlo < 0)   vlo = 0;
    if (vhi > 127) vhi = 127;
    const int n4 = (vhi - vlo + 1) << 5;   // nrows*128/4 float4s, <= 1024

    float acc[16];
    #pragma unroll
    for (int j = 0; j < 16; ++j) acc[j] = 0.0f;

    __syncthreads();   // trig tables ready

    for (int b = 0; b < NPROJ; ++b) {
        // stage row window [vlo, vhi] of projection b (contiguous, coalesced)
        {
            const float4* src = (const float4*)(wcb + b * NPIX + (vlo << 7));
            float4* dst = (float4*)sp;
            for (int i = tid; i < n4; i += 256) dst[i] = src[i];
        }
        __syncthreads();

        const float cb   = sc[b], sb = ss[b];
        const float t    = fx * cb + fy * sb;
        const float s    = fy * cb - fx * sb;
        const float invr = frcp(500.0f + t);
        const float pu   = fmaf(KPROJ * s, invr, 63.5f);
        const int   iu0  = (int)pu;            // pu in [11, 116]
        const float fu   = pu - (float)iu0;
        float w2 = 1000.0f * invr; w2 = w2 * w2;
        const float Kz   = KPROJ * invr;
        const int colbase = iu0 - (vlo << 7);

        #pragma unroll
        for (int j = 0; j < 16; ++j) {
            const float pv  = fmaf(Kz, zlo + (float)j, 63.5f);
            const int   iv0 = (int)pv;         // pv in [19, 108]
            const float fv  = pv - (float)iv0;
            const int   off = (iv0 << 7) + colbase;
            const float g00 = sp[off],       g01 = sp[off + 1];
            const float g10 = sp[off + 128], g11 = sp[off + 129];
            const float top = fmaf(fu, g01 - g00, g00);
            const float bot = fmaf(fu, g11 - g10, g10);
            const float val = fmaf(fv, bot - top, top);
            acc[j] = fmaf(val, w2, acc[j]);
        }
        __syncthreads();
    }

    const float a = prelu[0];
    #pragma unroll
    for (int j = 0; j < 16; ++j) {
        const float v = acc[j];
        out[((z0 + j) << 14) + (y << 7) + x] = (v >= 0.0f) ? v : a * v;
    }
}

// ---------------------------------------------------------------------------
extern "C" void kernel_launch(void* const* d_in, const int* in_sizes, int n_in,
                              void* d_out, int out_size, void* d_ws, size_t ws_size,
                              hipStream_t stream) {
    const float* sino  = (const float*)d_in[0];   // (1,1,96,96,192)
    const float* wgt   = (const float*)d_in[1];   // (1,96,96,192)
    const float* prelu = (const float*)d_in[2];   // (1,)
    float* deriv = (float*)d_ws;                  // 96*96*192 floats
    float* wcb   = deriv + NPROJ * SLICE;         // 96*128*128 floats
    float* out   = (float*)d_out;                 // 128^3 floats

    k_deriv<<<dim3(NPROJ * NANG), dim3(192), 0, stream>>>(sino, wgt, deriv);
    k_bp2d <<<dim3(NPROJ, 8),     dim3(256), 0, stream>>>(deriv, wcb);
    k_bp3d <<<dim3(64, 8),        dim3(256), 0, stream>>>(wcb, prelu, out);
}

// Round 2
// 245.774 us; speedup vs baseline: 1.0864x; 1.0864x over previous
//
#include <hip/hip_runtime.h>
#include <math.h>

#define NPROJ 96
#define NANG  96
#define DET   192
#define HH    128
#define WW    128
#define NPIX  (HH*WW)          // 16384
#define SLICE (NANG*DET)       // 18432

// DSD/DU = DSD/DV = 1000/3.5
#define KPROJ 285.7142857142857f
#define PITCH 132              // LDS row pitch (floats): breaks stride-128 bank aliasing

__device__ __forceinline__ float frcp(float x) { return __builtin_amdgcn_rcpf(x); }

// ---------------------------------------------------------------------------
// K1: deriv = grad_lastdim(sino * weight), rows of 192 along detector dim
// ---------------------------------------------------------------------------
__global__ __launch_bounds__(192) void k_deriv(const float* __restrict__ sino,
                                               const float* __restrict__ wgt,
                                               float* __restrict__ deriv) {
    __shared__ float row[DET];
    const int r = blockIdx.x;          // p*96 + a, 0..9215
    const int d = threadIdx.x;         // 0..191
    const int base = r * DET + d;
    row[d] = sino[base] * wgt[base];
    __syncthreads();
    float g;
    if (d == 0)           g = row[1] - row[0];
    else if (d == DET-1)  g = row[DET-1] - row[DET-2];
    else                  g = 0.5f * (row[d+1] - row[d-1]);
    deriv[base] = g;
}

// ---------------------------------------------------------------------------
// K2: 2D backprojection over 96 angles + 3D cosine weighting.
// grid (96 p, 16 pixel-chunks), block 256, 4 px/thread. Angles staged in
// chunks of 24 (18.4 KB LDS -> 8 blocks/CU instead of 2 with the full slice).
// pos = cos*x + sin*y + 95.5 is ALWAYS in [5.7, 185.3] -> no boundary masks.
// ---------------------------------------------------------------------------
#define ACHUNK 24
__global__ __launch_bounds__(256) void k_bp2d(const float* __restrict__ deriv,
                                              float* __restrict__ wcb) {
    __shared__ float sd[ACHUNK * DET];     // 18432 B
    __shared__ float sc[NANG], ss[NANG];
    const int p   = blockIdx.x;
    const int tid = threadIdx.x;

    if (tid < NANG) {
        float s_, c_;
        sincosf((float)tid * (float)(3.14159265358979323846 / 96.0), &s_, &c_);
        sc[tid] = c_; ss[tid] = s_;
    }

    const int pixbase = blockIdx.y * 1024;
    float acc[4], fx[4], fy[4];
    #pragma unroll
    for (int i = 0; i < 4; ++i) {
        const int pix = pixbase + i*256 + tid;
        fx[i] = (float)(pix & 127) - 63.5f;
        fy[i] = (float)(pix >> 7)  - 63.5f;
        acc[i] = 0.0f;
    }
    __syncthreads();   // trig ready (also guards sd below)

    for (int chunk = 0; chunk < NANG/ACHUNK; ++chunk) {
        // stage 24 angle-rows: 4608 floats = 1152 float4
        {
            const float4* src = (const float4*)(deriv + p * SLICE + chunk * (ACHUNK*DET));
            float4* dst = (float4*)sd;
            #pragma unroll
            for (int i = 0; i < 5; ++i) {
                const int idx = tid + i*256;
                if (idx < (ACHUNK*DET)/4) dst[idx] = src[idx];
            }
        }
        __syncthreads();

        for (int la = 0; la < ACHUNK; ++la) {
            const int a = chunk * ACHUNK + la;
            const float cb = sc[a], sb = ss[a];
            const float* rowp = sd + la * DET;
            #pragma unroll
            for (int i = 0; i < 4; ++i) {
                const float pos = cb * fx[i] + sb * fy[i] + 95.5f;
                const int   i0  = (int)pos;          // pos > 0 always
                const float f   = pos - (float)i0;
                const float g0  = rowp[i0];
                const float g1  = rowp[i0 + 1];
                acc[i] += fmaf(f, g1 - g0, g0);
            }
        }
        __syncthreads();
    }

    #pragma unroll
    for (int i = 0; i < 4; ++i) {
        const int pix = pixbase + i*256 + tid;
        const float w = 1000.0f * rsqrtf(1000000.0f + fx[i]*fx[i] + fy[i]*fy[i]);
        wcb[p * NPIX + pix] = acc[i] * w;
    }
}

// ---------------------------------------------------------------------------
// K3: 3D cone-beam backprojection + PReLU.
// grid (64 y-pairs, 32 z-chunks), block 256: thread = (x, y in pair), 4 z's.
// 2048 blocks = 8 blocks/CU -> waves-limited full occupancy.
// Per beta, stage the v-row window for this z-chunk (<=19 rows, ~10 KB,
// pitch-132 padded against stride-128 bank conflicts). pu/pv always interior.
// ---------------------------------------------------------------------------
__global__ __launch_bounds__(256) void k_bp3d(const float* __restrict__ wcb,
                                              const float* __restrict__ prelu,
                                              float* __restrict__ out) {
    __shared__ float sp[20 * PITCH];   // 10560 B
    __shared__ float sc[NPROJ], ss[NPROJ];
    const int tid = threadIdx.x;
    const int x   = tid & 127;
    const int y   = (blockIdx.x << 1) | (tid >> 7);
    const int z0  = blockIdx.y << 2;

    if (tid < NPROJ) {
        float s_, c_;
        sincosf((float)tid * (float)(2.0 * 3.14159265358979323846 / 96.0), &s_, &c_);
        sc[tid] = c_; ss[tid] = s_;
    }

    const float fx  = (float)x - 63.5f;
    const float fy  = (float)y - 63.5f;
    const float zlo = (float)z0 - 63.5f;
    const float zhi = zlo + 3.0f;

    // v-window for this z-chunk: pv = 63.5 + K*z', K in [0.4844, 0.6966]
    const float KMIN = 0.4843f, KMAX = 0.6967f;
    const float c0 = KMIN * zlo, c1 = KMAX * zlo, c2 = KMIN * zhi, c3 = KMAX * zhi;
    const float mn = fminf(fminf(c0, c1), fminf(c2, c3));
    const float mx = fmaxf(fmaxf(c0, c1), fmaxf(c2, c3));
    int vlo = (int)floorf(63.5f + mn) - 1;
    int vhi = (int)floorf(63.5f + mx) + 2;
    if (vlo < 0)   vlo = 0;
    if (vhi > 127) vhi = 127;
    const int nrow4 = (vhi - vlo + 1) << 5;  // rows * 32 float4s per row, <= 608

    float acc[4];
    #pragma unroll
    for (int j = 0; j < 4; ++j) acc[j] = 0.0f;

    __syncthreads();   // trig tables ready

    for (int b = 0; b < NPROJ; ++b) {
        // stage row window [vlo, vhi] of projection b into pitch-132 LDS
        {
            const float* src = wcb + b * NPIX + (vlo << 7);
            for (int i = tid; i < nrow4; i += 256) {
                const int row = i >> 5, c4 = i & 31;
                ((float4*)(sp + row * PITCH))[c4] =
                    ((const float4*)(src + (row << 7)))[c4];
            }
        }
        __syncthreads();

        const float cb   = sc[b], sb = ss[b];
        const float t    = fx * cb + fy * sb;
        const float s    = fy * cb - fx * sb;
        const float invr = frcp(500.0f + t);
        const float pu   = fmaf(KPROJ * s, invr, 63.5f);
        const int   iu0  = (int)pu;            // pu in [11, 116]
        const float fu   = pu - (float)iu0;
        float w2 = 1000.0f * invr; w2 = w2 * w2;
        const float Kz   = KPROJ * invr;

        #pragma unroll
        for (int j = 0; j < 4; ++j) {
            const float pv  = fmaf(Kz, zlo + (float)j, 63.5f);
            const int   iv0 = (int)pv;         // pv in [19, 108]
            const float fv  = pv - (float)iv0;
            const int   ivr = iv0 - vlo;
            const int   off = ivr * PITCH + iu0;
            const float g00 = sp[off],         g01 = sp[off + 1];
            const float g10 = sp[off + PITCH], g11 = sp[off + PITCH + 1];
            const float top = fmaf(fu, g01 - g00, g00);
            const float bot = fmaf(fu, g11 - g10, g10);
            const float val = fmaf(fv, bot - top, top);
            acc[j] = fmaf(val, w2, acc[j]);
        }
        __syncthreads();
    }

    const float a = prelu[0];
    #pragma unroll
    for (int j = 0; j < 4; ++j) {
        const float v = acc[j];
        out[((z0 + j) << 14) + (y << 7) + x] = (v >= 0.0f) ? v : a * v;
    }
}

// ---------------------------------------------------------------------------
extern "C" void kernel_launch(void* const* d_in, const int* in_sizes, int n_in,
                              void* d_out, int out_size, void* d_ws, size_t ws_size,
                              hipStream_t stream) {
    const float* sino  = (const float*)d_in[0];   // (1,1,96,96,192)
    const float* wgt   = (const float*)d_in[1];   // (1,96,96,192)
    const float* prelu = (const float*)d_in[2];   // (1,)
    float* deriv = (float*)d_ws;                  // 96*96*192 floats
    float* wcb   = deriv + NPROJ * SLICE;         // 96*128*128 floats
    float* out   = (float*)d_out;                 // 128^3 floats

    k_deriv<<<dim3(NPROJ * NANG), dim3(192), 0, stream>>>(sino, wgt, deriv);
    k_bp2d <<<dim3(NPROJ, 16),    dim3(256), 0, stream>>>(deriv, wcb);
    k_bp3d <<<dim3(64, 32),       dim3(256), 0, stream>>>(wcb, prelu, out);
}